// Round 1
// baseline (598.096 us; speedup 1.0000x reference)
//
#include <hip/hip_runtime.h>
#include <hip/hip_bf16.h>
#include <math.h>

// ---------------------------------------------------------------------------
// KAN-Conv CIFAR net on gfx950.
// Pipeline per layer: precompute_act (silu + 6 spline bases per pixel, stored
// as 8 floats) -> fused conv3x3(pad1) + KAN-linear + maxpool2.
// Final: 256x512 @ 512x100 linear + bias.
// ---------------------------------------------------------------------------

#define BATCH 256

// B-spline basis, order 3, grid_size 3 -> 6 basis values.
// Matches jnp: grid[i] = i_rel * (2/3) - 1 in fp32, indicator [g_i, g_{i+1}).
__device__ __forceinline__ void bspline_basis(float x, float out[6]) {
    const float h = 2.0f / 3.0f;
    float g[10];
#pragma unroll
    for (int i = 0; i < 10; ++i) g[i] = (float)(i - 3) * h - 1.0f;
    float b[9];
#pragma unroll
    for (int i = 0; i < 9; ++i) b[i] = (x >= g[i] && x < g[i + 1]) ? 1.0f : 0.0f;
#pragma unroll
    for (int j = 1; j <= 3; ++j) {
#pragma unroll
        for (int i = 0; i + j < 9; ++i) {
            float left  = (x - g[i]) / (g[i + j] - g[i]);
            float right = (g[i + j + 1] - x) / (g[i + j + 1] - g[i + 1]);
            b[i] = left * b[i] + right * b[i + 1];   // b[i+1] is old value (ascending i)
        }
    }
#pragma unroll
    for (int i = 0; i < 6; ++i) out[i] = b[i];
}

// Per-pixel activation record: [silu(x), b0..b5, 0]  (8 floats, float4-aligned)
__global__ __launch_bounds__(256) void precompute_act(const float* __restrict__ x,
                                                      float* __restrict__ act, int n) {
    int i = blockIdx.x * blockDim.x + threadIdx.x;
    if (i >= n) return;
    float v = x[i];
    float silu = v / (1.0f + expf(-v));
    float bs[6];
    bspline_basis(v, bs);
    float4* o = (float4*)(act + (size_t)i * 8);
    o[0] = make_float4(silu, bs[0], bs[1], bs[2]);
    o[1] = make_float4(bs[3], bs[4], bs[5], 0.0f);
}

// Fused KAN conv3x3 (pad 1) + maxpool 2x2.
// act:  [B, C, H, W, 8]   (silu + bases per input pixel)
// out:  [B, O, H/2, W/2]
template <int C, int O, int H, int W>
__global__ __launch_bounds__(256) void kan_conv_pool(const float* __restrict__ act,
                                                     const float* __restrict__ base_w,   // [O, C*9]
                                                     const float* __restrict__ spline_w, // [O, C*9, 6]
                                                     const float* __restrict__ scaler,   // [O, C*9]
                                                     float* __restrict__ out) {
    constexpr int PH = H / 2, PW = W / 2;
    constexpr int F = C * 9;
    int idx = blockIdx.x * blockDim.x + threadIdx.x;
    if (idx >= BATCH * O * PH * PW) return;
    int pw = idx % PW;
    int t  = idx / PW;
    int ph = t % PH; t /= PH;
    int o  = t % O;
    int b  = t / O;

    // Basis for zero-padded pixels (x = 0): nonzero! silu(0) = 0 though.
    float zb[6];
    bspline_basis(0.0f, zb);

    const float* bw_row = base_w + (size_t)o * F;
    const float* sc_row = scaler + (size_t)o * F;
    const float* sw_row = spline_w + (size_t)o * F * 6;

    float acc00 = 0.f, acc01 = 0.f, acc10 = 0.f, acc11 = 0.f;

    for (int c = 0; c < C; ++c) {
#pragma unroll
        for (int ky = 0; ky < 3; ++ky) {
#pragma unroll
            for (int kx = 0; kx < 3; ++kx) {
                int f = c * 9 + ky * 3 + kx;
                float bw = bw_row[f];
                float sc = sc_row[f];
                float s0 = sw_row[f * 6 + 0] * sc;
                float s1 = sw_row[f * 6 + 1] * sc;
                float s2 = sw_row[f * 6 + 2] * sc;
                float s3 = sw_row[f * 6 + 3] * sc;
                float s4 = sw_row[f * 6 + 4] * sc;
                float s5 = sw_row[f * 6 + 5] * sc;
#pragma unroll
                for (int dy = 0; dy < 2; ++dy) {
#pragma unroll
                    for (int dx = 0; dx < 2; ++dx) {
                        int hh = 2 * ph + dy + ky - 1;
                        int ww = 2 * pw + dx + kx - 1;
                        float contrib;
                        if ((unsigned)hh < (unsigned)H && (unsigned)ww < (unsigned)W) {
                            const float4* ap = (const float4*)(act +
                                (((size_t)(b * C + c) * H + hh) * W + ww) * 8);
                            float4 lo = ap[0];
                            float4 hi = ap[1];
                            contrib = lo.x * bw + lo.y * s0 + lo.z * s1 + lo.w * s2 +
                                      hi.x * s3 + hi.y * s4 + hi.z * s5;
                        } else {
                            contrib = zb[0] * s0 + zb[1] * s1 + zb[2] * s2 +
                                      zb[3] * s3 + zb[4] * s4 + zb[5] * s5;
                        }
                        if (dy == 0 && dx == 0) acc00 += contrib;
                        else if (dy == 0 && dx == 1) acc01 += contrib;
                        else if (dy == 1 && dx == 0) acc10 += contrib;
                        else acc11 += contrib;
                    }
                }
            }
        }
    }
    float m = fmaxf(fmaxf(acc00, acc01), fmaxf(acc10, acc11));
    out[(((size_t)b * O + o) * PH + ph) * PW + pw] = m;
}

// out[n,o] = dot(h[n,:512], w[o,:512]) + bias[o]
__global__ __launch_bounds__(256) void linear_kernel(const float* __restrict__ h,
                                                     const float* __restrict__ w,
                                                     const float* __restrict__ bias,
                                                     float* __restrict__ out) {
    int idx = blockIdx.x * blockDim.x + threadIdx.x;
    if (idx >= BATCH * 100) return;
    int o = idx % 100;
    int n = idx / 100;
    const float4* hp = (const float4*)(h + (size_t)n * 512);
    const float4* wp = (const float4*)(w + (size_t)o * 512);
    float acc = 0.f;
#pragma unroll 4
    for (int i = 0; i < 128; ++i) {
        float4 a = hp[i];
        float4 b = wp[i];
        acc += a.x * b.x + a.y * b.y + a.z * b.z + a.w * b.w;
    }
    out[idx] = acc + bias[o];
}

extern "C" void kernel_launch(void* const* d_in, const int* in_sizes, int n_in,
                              void* d_out, int out_size, void* d_ws, size_t ws_size,
                              hipStream_t stream) {
    const float* x        = (const float*)d_in[0];   // [256,3,32,32]
    const float* c1_bw    = (const float*)d_in[1];   // [8,27]
    const float* c1_sw    = (const float*)d_in[2];   // [8,27,6]
    const float* c1_sc    = (const float*)d_in[3];   // [8,27]
    const float* c2_bw    = (const float*)d_in[4];   // [16,72]
    const float* c2_sw    = (const float*)d_in[5];   // [16,72,6]
    const float* c2_sc    = (const float*)d_in[6];   // [16,72]
    const float* c3_bw    = (const float*)d_in[7];   // [32,144]
    const float* c3_sw    = (const float*)d_in[8];   // [32,144,6]
    const float* c3_sc    = (const float*)d_in[9];   // [32,144]
    const float* lin_w    = (const float*)d_in[10];  // [100,512]
    const float* lin_b    = (const float*)d_in[11];  // [100]
    float* out = (float*)d_out;                      // [256,100]

    float* ws = (float*)d_ws;
    // Workspace layout (floats). act region reused across layers.
    // act: max(786432, 524288, 262144) * 8 = 6291456 floats
    float* act = ws;                       // 6291456 floats (25.2 MB)
    float* h1  = ws + 6291456;             // 256*8*16*16  = 524288
    float* h2  = h1 + 524288;              // 256*16*8*8   = 131072
    float* h3  = h2 + 131072;              // 256*32*4*4   = 131072
    // total: 7,077,888 floats = 28.3 MB

    const int BS = 256;

    // ---- Layer 1: [256,3,32,32] -> [256,8,16,16]
    {
        int n = BATCH * 3 * 32 * 32;                      // 786432
        precompute_act<<<(n + BS - 1) / BS, BS, 0, stream>>>(x, act, n);
        int nt = BATCH * 8 * 16 * 16;                     // 524288
        kan_conv_pool<3, 8, 32, 32><<<(nt + BS - 1) / BS, BS, 0, stream>>>(
            act, c1_bw, c1_sw, c1_sc, h1);
    }
    // ---- Layer 2: [256,8,16,16] -> [256,16,8,8]
    {
        int n = BATCH * 8 * 16 * 16;                      // 524288
        precompute_act<<<(n + BS - 1) / BS, BS, 0, stream>>>(h1, act, n);
        int nt = BATCH * 16 * 8 * 8;                      // 262144
        kan_conv_pool<8, 16, 16, 16><<<(nt + BS - 1) / BS, BS, 0, stream>>>(
            act, c2_bw, c2_sw, c2_sc, h2);
    }
    // ---- Layer 3: [256,16,8,8] -> [256,32,4,4]
    {
        int n = BATCH * 16 * 8 * 8;                       // 262144
        precompute_act<<<(n + BS - 1) / BS, BS, 0, stream>>>(h2, act, n);
        int nt = BATCH * 32 * 4 * 4;                      // 131072
        kan_conv_pool<16, 32, 8, 8><<<(nt + BS - 1) / BS, BS, 0, stream>>>(
            act, c3_bw, c3_sw, c3_sc, h3);
    }
    // ---- Final linear: [256,512] @ [100,512]^T + b -> [256,100]
    {
        int nt = BATCH * 100;                             // 25600
        linear_kernel<<<(nt + BS - 1) / BS, BS, 0, stream>>>(h3, lin_w, lin_b, out);
    }
}